// Round 9
// baseline (714.517 us; speedup 1.0000x reference)
//
#include <hip/hip_runtime.h>
#include <math.h>

#define NQ 12
#define LAYERS 8
#define BATCH 4096

// R8 post-mortem: allocator pins VGPR=128 (4 waves/EU) and spills ~750MB
// regardless of launch_bounds/waves_per_eu hints. Fix: restructure to FIT
// 128 VGPRs -> TWO waves per batch element (block=128), 32 amps/lane
// (64 state VGPRs + ~45 working).
//
// Amplitude flat index i (bit11..bit0): r4 r3 r2 r1 r0 | wv | l5..l0
//   wires 0..4  -> reg bits r4..r0  (in-register 2x2 gates)
//   wire  5     -> wave bit          (gate via 16KB LDS exchange)
//   wires 6..11 -> lane bits l5..l0  (shfl_xor butterfly gates)
// CNOT ring: (0,1)..(3,4) = free register renaming; (4,5) = odd-reg
// wave-swap via LDS; (5,6) merged into the sigma bpermute pass (^32 for
// wave 1); (6,7)..(10,11) = sigma(l)=l^((l>>1)&31); (11,0) = odd lanes
// swap r <-> r+16 (cndmask).
//
// MODE 0: d_out = float[B*4096] (real parts; harness casts complex64->f32).
// MODE 1: d_out = float2[B*4096] interleaved.
template <int MODE>
__global__ __launch_bounds__(128)
void qsim_kernel(const float* __restrict__ x,
                 const float* __restrict__ input_params,
                 const float* __restrict__ weights,
                 float* __restrict__ out, long long out_elems) {
  const int b = blockIdx.x;
  const int tid = threadIdx.x;
  const int lane = tid & 63;
  const int wv = (tid >> 6) & 1;

  // lane-contiguous exchange buffer: xch[wave][k][lane] -> conflict-free
  __shared__ float2 xch[2][16][64];

  float sr[32], si[32];
#pragma unroll
  for (int r = 0; r < 32; ++r) { sr[r] = 0.f; si[r] = 0.f; }
  sr[0] = (wv == 0 && lane == 0) ? 1.f : 0.f;

  // sigma composes CNOTs (6,7)..(10,11); wave1 folds in CNOT(5,6)'s ^32.
  const int sigma = lane ^ ((lane >> 1) & 31);
  const int srcLane = wv ? (sigma ^ 32) : sigma;

  const float* xb = x + b * (NQ * LAYERS);

#pragma unroll 1
  for (int l = 0; l < LAYERS; ++l) {
    // --- fused gate per wire: lane w (w<12) computes U_w = Rot_w * RY_w ---
    // U = [[g, -conj(h)], [h, conj(g)]]  (both waves compute identically)
    float gr, gi, hr, hi;
    {
      const int wi = (lane < NQ) ? lane : (NQ - 1);
      const int idx = l * NQ + wi;
      const float a = input_params[idx] * xb[idx];
      float sa, ca; sincosf(0.5f * a, &sa, &ca);
      const float phi = weights[idx * 3 + 0];
      const float th  = weights[idx * 3 + 1];
      const float om  = weights[idx * 3 + 2];
      float st, ct;    sincosf(0.5f * th, &st, &ct);
      float spp, cpp_; sincosf(0.5f * (phi + om), &spp, &cpp_);
      float smm, cmm;  sincosf(0.5f * (phi - om), &smm, &cmm);
      const float ar = ct * cpp_, ai = -ct * spp;
      const float br = st * cmm,  bi = -st * smm;
      gr = ar * ca - br * sa;
      gi = ai * ca + bi * sa;
      hr = br * ca + ar * sa;
      hi = bi * ca - ai * sa;
    }

    // --- reg-bit gates: wires 0..4 (mask 16>>w), all indices static ---
#pragma unroll
    for (int w = 0; w < 5; ++w) {
      const float Gr = __shfl(gr, w), Gi = __shfl(gi, w);
      const float Hr = __shfl(hr, w), Hi = __shfl(hi, w);
      const int m = 16 >> w;
#pragma unroll
      for (int r0 = 0; r0 < 32; ++r0) {
        if (r0 & m) continue;
        const int r1 = r0 | m;
        const float s0r = sr[r0], s0i = si[r0];
        const float s1r = sr[r1], s1i = si[r1];
        sr[r0] = Gr * s0r - Gi * s0i - Hr * s1r - Hi * s1i;
        si[r0] = Gr * s0i + Gi * s0r + Hi * s1r - Hr * s1i;
        sr[r1] = Hr * s0r - Hi * s0i + Gr * s1r + Gi * s1i;
        si[r1] = Hr * s0i + Hi * s0r + Gr * s1i - Gi * s1r;
      }
    }

    // --- wave-bit gate: wire 5, LDS exchange in two 16-reg chunks ---
    {
      const float Gr = __shfl(gr, 5), Gi = __shfl(gi, 5);
      const float Hr = __shfl(hr, 5), Hi = __shfl(hi, 5);
      const float Dr  = Gr;
      const float Di  = wv ? -Gi : Gi;
      const float Or_ = wv ?  Hr : -Hr;
      const float Oi  = Hi;
#pragma unroll
      for (int c = 0; c < 2; ++c) {
#pragma unroll
        for (int k = 0; k < 16; ++k)
          xch[wv][k][lane] = make_float2(sr[c * 16 + k], si[c * 16 + k]);
        __syncthreads();
#pragma unroll
        for (int k = 0; k < 16; ++k) {
          const float2 p = xch[wv ^ 1][k][lane];
          const int r = c * 16 + k;
          const float mr = sr[r], mi = si[r];
          sr[r] = Dr * mr - Di * mi + Or_ * p.x - Oi * p.y;
          si[r] = Dr * mi + Di * mr + Or_ * p.y + Oi * p.x;
        }
        __syncthreads();
      }
    }

    // --- lane-bit gates: wires 6..11 (runtime w-loop bounds code size) ---
#pragma unroll 1
    for (int w = 6; w < 12; ++w) {
      const float Gr = __shfl(gr, w), Gi = __shfl(gi, w);
      const float Hr = __shfl(hr, w), Hi = __shfl(hi, w);
      const int lb = 11 - w;
      const int mask = 1 << lb;
      const int bset = (lane >> lb) & 1;
      const float Dr  = Gr;
      const float Di  = bset ? -Gi : Gi;
      const float Or_ = bset ?  Hr : -Hr;
      const float Oi  = Hi;
#pragma unroll
      for (int r = 0; r < 32; ++r) {
        const float pr = __shfl_xor(sr[r], mask);
        const float pi = __shfl_xor(si[r], mask);
        const float mr = sr[r], mi = si[r];
        sr[r] = Dr * mr - Di * mi + Or_ * pr - Oi * pi;
        si[r] = Dr * mi + Di * mr + Or_ * pi + Oi * pr;
      }
    }

    // --- CNOT ring, order (0,1)..(11,0) ---
    // (0,1)..(3,4): in-place compile-time reg swaps (free renaming).
#pragma unroll
    for (int w = 0; w < 4; ++w) {
      const int cm = 16 >> w, tm = cm >> 1;
#pragma unroll
      for (int r = 0; r < 32; ++r) {
        if ((r & cm) && !(r & tm)) {
          const int p = r | tm;
          float t;
          t = sr[r]; sr[r] = sr[p]; sr[p] = t;
          t = si[r]; si[r] = si[p]; si[p] = t;
        }
      }
    }
    // (4,5): control r0 -> odd regs swap between waves via LDS.
#pragma unroll
    for (int k = 0; k < 16; ++k)
      xch[wv][k][lane] = make_float2(sr[2 * k + 1], si[2 * k + 1]);
    __syncthreads();
#pragma unroll
    for (int k = 0; k < 16; ++k) {
      const float2 p = xch[wv ^ 1][k][lane];
      sr[2 * k + 1] = p.x; si[2 * k + 1] = p.y;
    }
    __syncthreads();
    // (5,6)+(6,7)..(10,11): single shuffle pass, wave-uniform source.
#pragma unroll
    for (int r = 0; r < 32; ++r) {
      sr[r] = __shfl(sr[r], srcLane);
      si[r] = __shfl(si[r], srcLane);
    }
    // (11,0): control lane bit0, target r4 -> odd lanes swap r <-> r+16.
    {
      const bool odd = (lane & 1) != 0;
#pragma unroll
      for (int r = 0; r < 16; ++r) {
        const float a0 = sr[r], b0 = sr[r + 16];
        sr[r]      = odd ? b0 : a0;
        sr[r + 16] = odd ? a0 : b0;
        const float a1 = si[r], b1 = si[r + 16];
        si[r]      = odd ? b1 : a1;
        si[r + 16] = odd ? a1 : b1;
      }
    }
  }

  // Store: idx = b*4096 + (r<<7) + (wv<<6) + lane -- 128 contiguous
  // floats per r per block, fully coalesced. Bounds-guarded.
  const long long base = ((long long)b << NQ) + (wv << 6) + lane;
  if (MODE == 0) {
#pragma unroll
    for (int r = 0; r < 32; ++r) {
      const long long idx = base + ((long long)r << 7);
      if (idx < out_elems) out[idx] = sr[r];
    }
  } else {
    float2* ob = (float2*)out;
#pragma unroll
    for (int r = 0; r < 32; ++r) {
      const long long idx = base + ((long long)r << 7);
      if (2 * idx + 1 < out_elems) ob[idx] = make_float2(sr[r], si[r]);
    }
  }
}

extern "C" void kernel_launch(void* const* d_in, const int* in_sizes, int n_in,
                              void* d_out, int out_size, void* d_ws, size_t ws_size,
                              hipStream_t stream) {
  const float* x  = (const float*)d_in[0];
  const float* ip = (const float*)d_in[1];
  const float* w  = (const float*)d_in[2];
  float* out = (float*)d_out;
  (void)in_sizes; (void)n_in; (void)d_ws; (void)ws_size;
  const long long total = (long long)BATCH << NQ;   // 16,777,216 amplitudes
  if ((long long)out_size == 2 * total) {
    qsim_kernel<1><<<BATCH, 128, 0, stream>>>(x, ip, w, out, (long long)out_size);
  } else {
    qsim_kernel<0><<<BATCH, 128, 0, stream>>>(x, ip, w, out, (long long)out_size);
  }
}